// Round 1
// baseline (124.444 us; speedup 1.0000x reference)
//
#include <hip/hip_runtime.h>

// ClusteringAffinity: out[n,c] = exp(-min_j (f[n]-W[c,j])^2 / 10) for c<100,
// out[n,100] = rw (pairwise-variance regularizer over the 500 centers).
//
// rw via power sums over the 500 scalar centers:
//   S1 = sum_{i<j} (wi-wj)^2   = mc*p2 - p1^2
//   Sq = sum_{i<j} (wi-wj)^4   = mc*p4 - 4*p3*p1 + 3*p2^2
//   mu = S1/P, rw = Sq/P - mu^2,  P = (mc^2-mc)/2

static constexpr int N_    = 262144;
static constexpr int C_    = 100;
static constexpr int M_    = 5;
static constexpr int COLS  = C_ + 1;   // 101
static constexpr int MC_   = C_ * M_;  // 500
static constexpr int K_    = 8;        // rows per thread
static constexpr float SIGMA_INV = 0.1f;

__global__ __launch_bounds__(512)
void rw_kernel(const float* __restrict__ W, float* __restrict__ ws) {
    __shared__ double s1[512], s2[512], s3[512], s4[512];
    const int tid = threadIdx.x;
    double w = 0.0;
    if (tid < MC_) w = (double)W[tid];
    const double w2 = w * w;
    s1[tid] = w;
    s2[tid] = w2;
    s3[tid] = w2 * w;
    s4[tid] = w2 * w2;
    __syncthreads();
    for (int off = 256; off > 0; off >>= 1) {
        if (tid < off) {
            s1[tid] += s1[tid + off];
            s2[tid] += s2[tid + off];
            s3[tid] += s3[tid + off];
            s4[tid] += s4[tid + off];
        }
        __syncthreads();
    }
    if (tid == 0) {
        const double p1 = s1[0], p2 = s2[0], p3 = s3[0], p4 = s4[0];
        const double mc = (double)MC_;
        const double P  = 0.5 * (mc * mc - mc);
        const double S1 = mc * p2 - p1 * p1;
        const double Sq = mc * p4 - 4.0 * p3 * p1 + 3.0 * p2 * p2;
        const double mu = S1 / P;
        const double rw = Sq / P - mu * mu;
        ws[0] = (float)rw;
    }
}

__global__ __launch_bounds__(256)
void affinity_kernel(const float* __restrict__ f,
                     const float* __restrict__ W,
                     const float* __restrict__ ws,
                     float* __restrict__ out) {
    const int T = (N_ / K_) * COLS;  // 3,309,568 threads
    const int t = blockIdx.x * 256 + threadIdx.x;
    if (t >= T) return;

    const unsigned g = (unsigned)t / (unsigned)COLS;   // row group (magic div)
    const int      c = t - (int)g * COLS;              // 0..100

    // Clamp W index for the rw column (branch-free; result selected out below).
    const int wc = (c < C_) ? c : 0;
    const float w0 = W[wc * M_ + 0];
    const float w1 = W[wc * M_ + 1];
    const float w2 = W[wc * M_ + 2];
    const float w3 = W[wc * M_ + 3];
    const float w4 = W[wc * M_ + 4];
    const float rw = ws[0];

    // 8 consecutive f values for this row group: two broadcast float4 loads.
    const float4* f4 = (const float4*)f;
    const float4 fa = f4[g * 2 + 0];
    const float4 fb = f4[g * 2 + 1];
    const float fv[K_] = {fa.x, fa.y, fa.z, fa.w, fb.x, fb.y, fb.z, fb.w};

    float* orow = out + (size_t)g * K_ * COLS + c;
    const bool is_dist = (c < C_);
#pragma unroll
    for (int k = 0; k < K_; ++k) {
        const float fk = fv[k];
        const float d0 = fk - w0, d1 = fk - w1, d2 = fk - w2,
                    d3 = fk - w3, d4 = fk - w4;
        const float m01 = fminf(d0 * d0, d1 * d1);
        const float m23 = fminf(d2 * d2, d3 * d3);
        const float mv  = fminf(fminf(m01, m23), d4 * d4);
        const float v   = __expf(-mv * SIGMA_INV);
        orow[(size_t)k * COLS] = is_dist ? v : rw;
    }
}

extern "C" void kernel_launch(void* const* d_in, const int* in_sizes, int n_in,
                              void* d_out, int out_size, void* d_ws, size_t ws_size,
                              hipStream_t stream) {
    const float* f  = (const float*)d_in[0];   // (262144, 1) fp32
    const float* W  = (const float*)d_in[1];   // (100, 5, 1) fp32
    float*       out = (float*)d_out;          // (262144, 101) fp32
    float*       ws  = (float*)d_ws;

    rw_kernel<<<1, 512, 0, stream>>>(W, ws);

    const int T = (N_ / K_) * COLS;
    const int grid = (T + 255) / 256;
    affinity_kernel<<<grid, 256, 0, stream>>>(f, W, ws, out);
}

// Round 2
// 119.723 us; speedup vs baseline: 1.0394x; 1.0394x over previous
//
#include <hip/hip_runtime.h>

// ClusteringAffinity: out[n,c] = exp(-min_j (f[n]-W[c,j])^2 / 10) for c<100,
// out[n,100] = rw (pairwise-variance regularizer over the 500 centers).
//
// R1: scalar dword stores (COLS=101 odd -> no aligned float4 per row) ran the
// write stream at ~1-2 TB/s vs the 6.4 TB/s the harness fill achieves.
// R2 structure: compute a 64-row x 101-col tile into LDS (compute mapping:
// one column per thread, W amortized over 32 rows), then stream the tile to
// global as contiguous 16B-aligned float4s (tile byte base = blk*25856 % 16 == 0).

static constexpr int N_    = 262144;
static constexpr int C_    = 100;
static constexpr int M_    = 5;
static constexpr int COLS  = C_ + 1;       // 101
static constexpr int MC_   = C_ * M_;      // 500
static constexpr int ROWS  = 64;           // rows per tile/block
static constexpr int TILE  = ROWS * COLS;  // 6464 floats = 25856 B (16B-aligned tiles)
static constexpr float SIGMA_INV = 0.1f;

__global__ __launch_bounds__(512)
void rw_kernel(const float* __restrict__ W, float* __restrict__ ws) {
    __shared__ double s1[512], s2[512], s3[512], s4[512];
    const int tid = threadIdx.x;
    double w = 0.0;
    if (tid < MC_) w = (double)W[tid];
    const double w2 = w * w;
    s1[tid] = w;
    s2[tid] = w2;
    s3[tid] = w2 * w;
    s4[tid] = w2 * w2;
    __syncthreads();
    for (int off = 256; off > 0; off >>= 1) {
        if (tid < off) {
            s1[tid] += s1[tid + off];
            s2[tid] += s2[tid + off];
            s3[tid] += s3[tid + off];
            s4[tid] += s4[tid + off];
        }
        __syncthreads();
    }
    if (tid == 0) {
        const double p1 = s1[0], p2 = s2[0], p3 = s3[0], p4 = s4[0];
        const double mc = (double)MC_;
        const double P  = 0.5 * (mc * mc - mc);
        const double S1 = mc * p2 - p1 * p1;                      // sum_{i<j} (wi-wj)^2
        const double Sq = mc * p4 - 4.0 * p3 * p1 + 3.0 * p2 * p2; // sum_{i<j} (wi-wj)^4
        const double mu = S1 / P;
        ws[0] = (float)(Sq / P - mu * mu);
    }
}

__global__ __launch_bounds__(256)
void affinity_kernel(const float* __restrict__ f,
                     const float* __restrict__ W,
                     const float* __restrict__ ws,
                     float* __restrict__ out) {
    __shared__ __align__(16) float tile[TILE];
    const int t  = threadIdx.x;
    const int n0 = blockIdx.x * ROWS;

    // ---- compute phase: threads 0..201 each own one column for 32 rows ----
    if (t < 2 * COLS) {
        const int rh = (t >= COLS) ? 1 : 0;       // row half: rows rh*32..rh*32+31
        const int c  = t - rh * COLS;             // 0..100

        // 32 consecutive f values: 8 aligned float4 loads (L1-broadcast across threads)
        float fv[32];
        const float4* f4 = (const float4*)(f + n0 + rh * 32);
#pragma unroll
        for (int q = 0; q < 8; ++q) {
            const float4 v = f4[q];
            fv[q * 4 + 0] = v.x; fv[q * 4 + 1] = v.y;
            fv[q * 4 + 2] = v.z; fv[q * 4 + 3] = v.w;
        }

        const int wc = (c < C_) ? c : 0;          // branch-free rw-column handling
        const float w0 = W[wc * M_ + 0];
        const float w1 = W[wc * M_ + 1];
        const float w2 = W[wc * M_ + 2];
        const float w3 = W[wc * M_ + 3];
        const float w4 = W[wc * M_ + 4];
        const float rw = ws[0];
        const bool is_dist = (c < C_);

        float* trow = tile + rh * 32 * COLS + c;
#pragma unroll
        for (int i = 0; i < 32; ++i) {
            const float fk = fv[i];
            const float d0 = fk - w0, d1 = fk - w1, d2 = fk - w2,
                        d3 = fk - w3, d4 = fk - w4;
            const float m01 = fminf(d0 * d0, d1 * d1);
            const float m23 = fminf(d2 * d2, d3 * d3);
            const float mv  = fminf(fminf(m01, m23), d4 * d4);
            const float v   = __expf(-mv * SIGMA_INV);
            trow[i * COLS] = is_dist ? v : rw;    // consecutive-c lanes -> no bank conflict
        }
    }
    __syncthreads();

    // ---- write phase: stream tile to global as aligned contiguous float4 ----
    const float4* lsrc = (const float4*)tile;
    float4* gdst = (float4*)(out + (size_t)n0 * COLS);  // blk*25856 B, 16B-aligned
    constexpr int NV = TILE / 4;  // 1616 float4s
#pragma unroll
    for (int q = 0; q < 6; ++q) {
        const int j = q * 256 + t;
        gdst[j] = lsrc[j];
    }
    {
        const int j = 6 * 256 + t;
        if (j < NV) gdst[j] = lsrc[j];
    }
}

extern "C" void kernel_launch(void* const* d_in, const int* in_sizes, int n_in,
                              void* d_out, int out_size, void* d_ws, size_t ws_size,
                              hipStream_t stream) {
    const float* f   = (const float*)d_in[0];   // (262144, 1) fp32
    const float* W   = (const float*)d_in[1];   // (100, 5, 1) fp32
    float*       out = (float*)d_out;           // (262144, 101) fp32
    float*       ws  = (float*)d_ws;

    rw_kernel<<<1, 512, 0, stream>>>(W, ws);
    affinity_kernel<<<N_ / ROWS, 256, 0, stream>>>(f, W, ws, out);
}